// Round 8
// baseline (242.175 us; speedup 1.0000x reference)
//
#include <hip/hip_runtime.h>

typedef short short8 __attribute__((ext_vector_type(8)));
typedef float floatx4 __attribute__((ext_vector_type(4)));

#define C_DIM 512
#define KQ_STRIDE 1040   // bytes per row of the LDS tile (512*2 + 16 pad)
#define SROWS 64         // rows per block, score kernel (2 blocks/CU)
#define ROWS 128         // rows per block, pv kernel (1 block/CU)

__device__ __forceinline__ unsigned short f2bf(float f) {
    unsigned u = __builtin_bit_cast(unsigned, f);
    u = u + 0x7fffu + ((u >> 16) & 1u);
    return (unsigned short)(u >> 16);
}

// Monotone uint key for argmax (max s, then min col); 9 low bits carry 511-col.
__device__ __forceinline__ unsigned skey(float s, int col) {
    unsigned u = __builtin_bit_cast(unsigned, s);
    u = ((int)u < 0) ? ~u : (u | 0x80000000u);
    return (u & ~0x1FFu) | (unsigned)(511 - col);
}

// ---- DPP 16-lane-row reductions on the VALU pipe ----
template <int CTRL>
__device__ __forceinline__ float dppAddF(float x) {
    int t = __builtin_amdgcn_update_dpp(0, __builtin_bit_cast(int, x), CTRL, 0xF, 0xF, true);
    return x + __builtin_bit_cast(float, t);
}
template <int CTRL>
__device__ __forceinline__ unsigned dppMaxU(unsigned x) {
    unsigned u = (unsigned)__builtin_amdgcn_update_dpp(0, (int)x, CTRL, 0xF, 0xF, true);
    return u > x ? u : x;
}
__device__ __forceinline__ float rowAdd16(float x) {
    x = dppAddF<0xB1>(x);
    x = dppAddF<0x4E>(x);
    x = dppAddF<0x124>(x);
    x = dppAddF<0x128>(x);
    return x;
}

// ---------------- pack kernel: keys/values -> B-frag order + passthrough copies + scal zero
__global__ __launch_bounds__(256) void pack_kernel(
    const float* __restrict__ keys, const float* __restrict__ values,
    unsigned short* __restrict__ keysFrag, unsigned short* __restrict__ valsFrag,
    float* __restrict__ keysOut, float* __restrict__ valsOut,
    float* __restrict__ scal) {
    int tid = blockIdx.x * 256 + threadIdx.x;
    if (tid < 65536) {
        int e  = tid & 32767;
        int l  = e & 63;
        int NT = (e >> 6) & 31;
        int kt = e >> 11;                           // 0..15
        int li = l & 15, q4 = l >> 4;
        unsigned short tmp[8];
        if (tid < 32768) {
            // score GEMM: B[k][n] = keys[n][k], keys is [M, C] row-major
            const float* s = keys + (size_t)(NT * 16 + li) * C_DIM + kt * 32 + q4 * 8;
#pragma unroll
            for (int j = 0; j < 8; j++) tmp[j] = f2bf(s[j]);
            unsigned short* d = keysFrag + ((size_t)(kt * 32 + NT) * 64 + l) * 8;
            *(ushort4*)d       = make_ushort4(tmp[0], tmp[1], tmp[2], tmp[3]);
            *(ushort4*)(d + 4) = make_ushort4(tmp[4], tmp[5], tmp[6], tmp[7]);
        } else {
            // PV GEMM: B[k][n] = values[k][n], k indexes M
#pragma unroll
            for (int j = 0; j < 8; j++)
                tmp[j] = f2bf(values[(size_t)(kt * 32 + q4 * 8 + j) * C_DIM + NT * 16 + li]);
            unsigned short* d = valsFrag + ((size_t)(kt * 32 + NT) * 64 + l) * 8;
            *(ushort4*)d       = make_ushort4(tmp[0], tmp[1], tmp[2], tmp[3]);
            *(ushort4*)(d + 4) = make_ushort4(tmp[4], tmp[5], tmp[6], tmp[7]);
        }
    } else {
        int ct = tid - 65536;                       // 0..32767
        if (ct == 0) { scal[0] = 0.f; scal[1] = 0.f; scal[2] = 0.f; }
#pragma unroll
        for (int i = 0; i < 4; i++) {
            int idx = ct + i * 32768;               // 0..131071 float4s
            if (idx < 65536) ((float4*)keysOut)[idx] = ((const float4*)keys)[idx];
            else             ((float4*)valsOut)[idx - 65536] = ((const float4*)values)[idx - 65536];
        }
    }
}

// ---------------- score kernel: 64 rows/block, 2 blocks/CU, load||GEMM chunk pipeline.
// Stages RAW bf16 key rows (norm deferred: s_true = s_raw * 1/||k||, applied at
// stats time — identical math, one fewer rounding). 8 chunks of 64 cols: stage
// chunk c while GEMM runs on chunk c-1's kts; key HBM latency hides under MFMA.
__global__ __launch_bounds__(512, 4) void score_kernel(
    const float* __restrict__ key,
    const unsigned short* __restrict__ keysFrag,
    float* __restrict__ outRQ,
    float* __restrict__ scal) {
    __shared__ char kq[SROWS * KQ_STRIDE];            // raw-k bf16 tile -> p tile
    __shared__ __align__(16) float stats[8][SROWS][4];
    __shared__ float invsh[SROWS];

    const int tid = threadIdx.x;
    const int w  = tid >> 6;
    const int l  = tid & 63;
    const int li = l & 15;
    const int q4 = l >> 4;
    const int row0 = blockIdx.x << 6;
    char* outb = (char*)outRQ;

    // staging rows: r0 = w*8+q4, r1 = w*8+4+q4 (16 lanes per row)
    const float4* src0 = (const float4*)(key + (size_t)(row0 + w * 8 + q4) * C_DIM);
    const float4* src1 = (const float4*)(key + (size_t)(row0 + w * 8 + 4 + q4) * C_DIM);

    floatx4 acc1[16];                                 // [rg*4+nt], rg 0..3
#pragma unroll
    for (int i = 0; i < 16; i++) acc1[i] = (floatx4){0.f, 0.f, 0.f, 0.f};

    const short8* kf = (const short8*)keysFrag;
    short8 bcur[4], bnxt[4];
#pragma unroll
    for (int nt = 0; nt < 4; nt++) bcur[nt] = kf[(size_t)((w * 4 + nt) * 64 + l)];

    float4 va0 = src0[li], va1 = src1[li];            // chunk 0
    float4 vb0, vb1;
    float ss0 = 0.f, ss1 = 0.f;

    for (int c = 0; c < 8; ++c) {
        if (c < 7) { vb0 = src0[(c + 1) * 16 + li]; vb1 = src1[(c + 1) * 16 + li]; }
        // stage chunk c (raw bf16) + accumulate sum-of-squares
        ss0 += va0.x * va0.x + va0.y * va0.y + va0.z * va0.z + va0.w * va0.w;
        ss1 += va1.x * va1.x + va1.y * va1.y + va1.z * va1.z + va1.w * va1.w;
        *(ushort4*)(kq + (w * 8 + q4) * KQ_STRIDE + c * 128 + li * 8) =
            make_ushort4(f2bf(va0.x), f2bf(va0.y), f2bf(va0.z), f2bf(va0.w));
        *(ushort4*)(kq + (w * 8 + 4 + q4) * KQ_STRIDE + c * 128 + li * 8) =
            make_ushort4(f2bf(va1.x), f2bf(va1.y), f2bf(va1.z), f2bf(va1.w));
        __syncthreads();
        // GEMM on this chunk's two kts
#pragma unroll
        for (int k2 = 0; k2 < 2; ++k2) {
            int kt = c * 2 + k2;
            if (kt < 15) {
#pragma unroll
                for (int nt = 0; nt < 4; nt++)
                    bnxt[nt] = kf[(size_t)(((kt + 1) * 32 + w * 4 + nt) * 64 + l)];
            }
#pragma unroll
            for (int rg = 0; rg < 4; ++rg) {
                short8 a = *(const short8*)(kq + (rg * 16 + li) * KQ_STRIDE + kt * 64 + q4 * 16);
#pragma unroll
                for (int nt = 0; nt < 4; nt++)
                    acc1[rg * 4 + nt] = __builtin_amdgcn_mfma_f32_16x16x32_bf16(
                        a, bcur[nt], acc1[rg * 4 + nt], 0, 0, 0);
            }
#pragma unroll
            for (int nt = 0; nt < 4; nt++) bcur[nt] = bnxt[nt];
        }
        va0 = vb0; va1 = vb1;
    }

    // finalize norms (wave-local) and publish
    ss0 = rowAdd16(ss0);
    ss1 = rowAdd16(ss1);
    if (li == 0) {
        invsh[w * 8 + q4]     = 1.0f / fmaxf(sqrtf(ss0), 1e-12f);
        invsh[w * 8 + 4 + q4] = 1.0f / fmaxf(sqrtf(ss1), 1e-12f);
    }
    __syncthreads();   // GEMM complete everywhere; invsh visible

    // ---- stats (scale by inv-norm, shiftless softmax, DPP reductions), acc1 -> p ----
#pragma unroll
    for (int rg = 0; rg < 4; rg++) {
#pragma unroll
        for (int reg = 0; reg < 4; reg++) {
            const int colbase = (w << 6) + li;
            const float inv = invsh[rg * 16 + q4 * 4 + reg];
            float s0 = acc1[rg * 4 + 0][reg] * inv;
            float s1 = acc1[rg * 4 + 1][reg] * inv;
            float s2 = acc1[rg * 4 + 2][reg] * inv;
            float s3 = acc1[rg * 4 + 3][reg] * inv;
            unsigned K  = skey(s0, colbase);
            unsigned K1 = skey(s1, colbase + 16);
            unsigned K2 = skey(s2, colbase + 32);
            unsigned K3 = skey(s3, colbase + 48);
            K = K1 > K ? K1 : K;
            K = K2 > K ? K2 : K;
            K = K3 > K ? K3 : K;
            float p0 = __expf(s0), p1 = __expf(s1), p2 = __expf(s2), p3 = __expf(s3);
            float z1 = (p0 + p1) + (p2 + p3);
            float e1 = p0 * s0 + p1 * s1 + p2 * s2 + p3 * s3;
            float z2 = p0 * p0 + p1 * p1 + p2 * p2 + p3 * p3;
            acc1[rg * 4 + 0][reg] = p0;
            acc1[rg * 4 + 1][reg] = p1;
            acc1[rg * 4 + 2][reg] = p2;
            acc1[rg * 4 + 3][reg] = p3;
            K = dppMaxU<0xB1>(K);  z1 = dppAddF<0xB1>(z1);  e1 = dppAddF<0xB1>(e1);  z2 = dppAddF<0xB1>(z2);
            K = dppMaxU<0x4E>(K);  z1 = dppAddF<0x4E>(z1);  e1 = dppAddF<0x4E>(e1);  z2 = dppAddF<0x4E>(z2);
            K = dppMaxU<0x124>(K); z1 = dppAddF<0x124>(z1); e1 = dppAddF<0x124>(e1); z2 = dppAddF<0x124>(z2);
            K = dppMaxU<0x128>(K); z1 = dppAddF<0x128>(z1); e1 = dppAddF<0x128>(e1); z2 = dppAddF<0x128>(z2);
            if (li == 0) {
                floatx4 sv;
                sv[0] = __builtin_bit_cast(float, K);
                sv[1] = z1; sv[2] = e1; sv[3] = z2;
                *(floatx4*)stats[w][rg * 16 + q4 * 4 + reg] = sv;
            }
        }
    }
    __syncthreads();

    // ---- merge + headers + scalars (wave 0; lane l owns row l), p -> kq (all waves) ----
    if (w == 0) {
        unsigned K; float z1, e1, z2;
        floatx4 v = *(const floatx4*)stats[0][l];
        K = __builtin_bit_cast(unsigned, v[0]); z1 = v[1]; e1 = v[2]; z2 = v[3];
#pragma unroll
        for (int p = 1; p < 8; p++) {
            floatx4 u = *(const floatx4*)stats[p][l];
            unsigned Ko = __builtin_bit_cast(unsigned, u[0]);
            K = Ko > K ? Ko : K;
            z1 += u[1]; e1 += u[2]; z2 += u[3];
        }
        float iz = 1.0f / z1;
        int idx = 511 - (int)(K & 0x1FFu);
        char* h = outb + (size_t)(row0 + l) * 2048;
        *(float*)h = iz; *(int*)(h + 4) = idx;
        unsigned um = (K >> 31) ? (K & 0x7FFFFFFFu) : ~K;
        um &= ~0x1FFu;
        float m1 = __builtin_bit_cast(float, um);
        float ent = __logf(z1) - e1 * iz;
        float con = __logf(z2) - 2.0f * m1;
#pragma unroll
        for (int msk = 1; msk < 64; msk <<= 1) {
            ent += __shfl_xor(ent, msk, 64);
            con += __shfl_xor(con, msk, 64);
        }
        if (l == 0) {
            atomicAdd(&scal[0], ent * (1.0f / 32768.0f));
            atomicAdd(&scal[2], con * (1.0f / 12800.0f));
        }
    }
#pragma unroll
    for (int rg = 0; rg < 4; rg++) {
#pragma unroll
        for (int reg = 0; reg < 4; reg++) {
            int r = rg * 16 + q4 * 4 + reg;
#pragma unroll
            for (int nt = 0; nt < 4; nt++) {
                int col = (w << 6) + nt * 16 + li;
                *(unsigned short*)(kq + r * KQ_STRIDE + col * 2) = f2bf(acc1[rg * 4 + nt][reg]);
            }
        }
    }
    __syncthreads();

    // ---- copy p tile -> global (second half of each outRQ row), coalesced 16B ----
#pragma unroll
    for (int it = 0; it < 8; it++) {
        int r = (w << 3) + it;
        float4 t = *(const float4*)(kq + r * KQ_STRIDE + l * 16);
        *(float4*)(outb + (size_t)(row0 + r) * 2048 + 1024 + l * 16) = t;
    }
}

// ---------------- gather kernel: mean((q_norm - values[idx])^2); idx from row headers.
// MUST run before pv_kernel (which overwrites the headers).
__global__ __launch_bounds__(256) void gather_kernel(
    const float* __restrict__ query,
    const float* __restrict__ values,
    const float* __restrict__ outRQ,
    float* __restrict__ scal) {
    __shared__ float gpart[4];
    const int tid = threadIdx.x;
    const int w = tid >> 6;
    const int l = tid & 63;
    const char* outb = (const char*)outRQ;
    const int row0 = blockIdx.x * 32;

    float gacc = 0.f;
#pragma unroll
    for (int rr = 0; rr < 8; rr++) {
        int r = row0 + w * 8 + rr;
        int idxr = *(const int*)(outb + (size_t)r * 2048 + 4);
        const float4* qr = (const float4*)(query + (size_t)r * C_DIM);
        float4 a = qr[l * 2], b = qr[l * 2 + 1];
        float ss = a.x * a.x + a.y * a.y + a.z * a.z + a.w * a.w +
                   b.x * b.x + b.y * b.y + b.z * b.z + b.w * b.w;
        ss = rowAdd16(ss);
        ss += __shfl_xor(ss, 16, 64);
        ss += __shfl_xor(ss, 32, 64);
        float inv = 1.0f / fmaxf(sqrtf(ss), 1e-12f);
        const float4* vr = (const float4*)(values + (size_t)idxr * C_DIM);
        float4 va = vr[l * 2], vb = vr[l * 2 + 1];
        float d;
        d = a.x * inv - va.x; gacc += d * d;
        d = a.y * inv - va.y; gacc += d * d;
        d = a.z * inv - va.z; gacc += d * d;
        d = a.w * inv - va.w; gacc += d * d;
        d = b.x * inv - vb.x; gacc += d * d;
        d = b.y * inv - vb.y; gacc += d * d;
        d = b.z * inv - vb.z; gacc += d * d;
        d = b.w * inv - vb.w; gacc += d * d;
    }
    gacc = rowAdd16(gacc);
    gacc += __shfl_xor(gacc, 16, 64);
    gacc += __shfl_xor(gacc, 32, 64);
    if (l == 0) gpart[w] = gacc;
    __syncthreads();
    if (tid == 0) {
        float s = gpart[0] + gpart[1] + gpart[2] + gpart[3];
        atomicAdd(&scal[1], s * (1.0f / (32768.0f * 512.0f)));
    }
}

// ---------------- pv kernel: chunked p staging || PV GEMM, scale by iz, store outRQ
__global__ __launch_bounds__(512, 2) void pv_kernel(
    const unsigned short* __restrict__ valsFrag,
    float* __restrict__ outRQ) {
    __shared__ char kq[ROWS * KQ_STRIDE];
    __shared__ float izsh[ROWS];

    const int tid = threadIdx.x;
    const int w  = tid >> 6;
    const int l  = tid & 63;
    const int li = l & 15;
    const int q4 = l >> 4;
    const int row0 = blockIdx.x << 7;
    char* outb = (char*)outRQ;

    if (tid < ROWS) izsh[tid] = *(const float*)(outb + (size_t)(row0 + tid) * 2048);

    // staging mapping: thread handles row sr, 32B at byte offset sq*32 of each 128B chunk
    const int sr = tid >> 2, sq = tid & 3;
    const char* psrc = outb + (size_t)(row0 + sr) * 2048 + 1024 + sq * 32;
    char* pdst = kq + sr * KQ_STRIDE + sq * 32;

    floatx4 acc2[32];
#pragma unroll
    for (int i = 0; i < 32; i++) acc2[i] = (floatx4){0.f, 0.f, 0.f, 0.f};

    const short8* vf = (const short8*)valsFrag;
    short8 bcur[4], bnxt[4];
#pragma unroll
    for (int nt = 0; nt < 4; nt++) bcur[nt] = vf[(size_t)((w * 4 + nt) * 64 + l)];

    float4 va0 = *(const float4*)(psrc);
    float4 va1 = *(const float4*)(psrc + 16);
    float4 vb0, vb1;

    for (int c = 0; c < 8; ++c) {
        if (c < 7) {
            vb0 = *(const float4*)(psrc + (c + 1) * 128);
            vb1 = *(const float4*)(psrc + (c + 1) * 128 + 16);
        }
        *(float4*)(pdst + c * 128)      = va0;
        *(float4*)(pdst + c * 128 + 16) = va1;
        __syncthreads();
#pragma unroll
        for (int k2 = 0; k2 < 2; ++k2) {
            int kt = c * 2 + k2;
            if (kt < 15) {
#pragma unroll
                for (int nt = 0; nt < 4; nt++)
                    bnxt[nt] = vf[(size_t)(((kt + 1) * 32 + w * 4 + nt) * 64 + l)];
            }
#pragma unroll
            for (int rg = 0; rg < 8; ++rg) {
                short8 a = *(const short8*)(kq + (rg * 16 + li) * KQ_STRIDE + kt * 64 + q4 * 16);
#pragma unroll
                for (int nt = 0; nt < 4; nt++)
                    acc2[rg * 4 + nt] = __builtin_amdgcn_mfma_f32_16x16x32_bf16(
                        a, bcur[nt], acc2[rg * 4 + nt], 0, 0, 0);
            }
#pragma unroll
            for (int nt = 0; nt < 4; nt++) bcur[nt] = bnxt[nt];
        }
        va0 = vb0; va1 = vb1;
    }

    // ---- scale by iz (LDS broadcast) and store; overwrites headers+p with result ----
#pragma unroll
    for (int rg = 0; rg < 8; rg++) {
#pragma unroll
        for (int reg = 0; reg < 4; reg++) {
            int r = rg * 16 + q4 * 4 + reg;
            float izr = izsh[r];
            float* orow = outRQ + (size_t)(row0 + r) * C_DIM + (w << 6) + li;
#pragma unroll
            for (int nt = 0; nt < 4; nt++) orow[nt * 16] = acc2[rg * 4 + nt][reg] * izr;
        }
    }
}

extern "C" void kernel_launch(void* const* d_in, const int* in_sizes, int n_in,
                              void* d_out, int out_size, void* d_ws, size_t ws_size,
                              hipStream_t stream) {
    (void)in_sizes; (void)n_in; (void)out_size; (void)ws_size;
    const float* key    = (const float*)d_in[0];
    const float* query  = (const float*)d_in[1];
    const float* keysIn = (const float*)d_in[2];
    const float* valsIn = (const float*)d_in[3];
    float* out = (float*)d_out;

    unsigned short* keysFrag = (unsigned short*)d_ws;            // 512 KB
    unsigned short* valsFrag = keysFrag + 512 * 512;             // 512 KB

    float* outRQ   = out;                       // 16777216 floats
    float* scal    = out + 16777216;            // entropy, gathering, contrast
    float* keysOut = out + 16777219;            // 262144 floats
    float* valsOut = keysOut + 262144;          // 262144 floats

    pack_kernel<<<384, 256, 0, stream>>>(keysIn, valsIn, keysFrag, valsFrag,
                                         keysOut, valsOut, scal);
    score_kernel<<<512, 512, 0, stream>>>(key, keysFrag, outRQ, scal);
    gather_kernel<<<1024, 256, 0, stream>>>(query, valsIn, outRQ, scal);
    pv_kernel<<<256, 512, 0, stream>>>(valsFrag, outRQ);
}

// Round 9
// 237.663 us; speedup vs baseline: 1.0190x; 1.0190x over previous
//
#include <hip/hip_runtime.h>

typedef short short8 __attribute__((ext_vector_type(8)));
typedef float floatx4 __attribute__((ext_vector_type(4)));

#define C_DIM 512
#define KQ_STRIDE 1040   // bytes per row of the LDS tile (512*2 + 16 pad)
#define ROWS 128         // rows per block (score + pv), 1 block/CU

__device__ __forceinline__ unsigned short f2bf(float f) {
    unsigned u = __builtin_bit_cast(unsigned, f);
    u = u + 0x7fffu + ((u >> 16) & 1u);
    return (unsigned short)(u >> 16);
}

// Monotone uint key for argmax (max s, then min col); 9 low bits carry 511-col.
__device__ __forceinline__ unsigned skey(float s, int col) {
    unsigned u = __builtin_bit_cast(unsigned, s);
    u = ((int)u < 0) ? ~u : (u | 0x80000000u);
    return (u & ~0x1FFu) | (unsigned)(511 - col);
}

// ---- DPP 16-lane-row reductions on the VALU pipe ----
template <int CTRL>
__device__ __forceinline__ float dppAddF(float x) {
    int t = __builtin_amdgcn_update_dpp(0, __builtin_bit_cast(int, x), CTRL, 0xF, 0xF, true);
    return x + __builtin_bit_cast(float, t);
}
template <int CTRL>
__device__ __forceinline__ unsigned dppMaxU(unsigned x) {
    unsigned u = (unsigned)__builtin_amdgcn_update_dpp(0, (int)x, CTRL, 0xF, 0xF, true);
    return u > x ? u : x;
}
__device__ __forceinline__ float rowAdd16(float x) {
    x = dppAddF<0xB1>(x);
    x = dppAddF<0x4E>(x);
    x = dppAddF<0x124>(x);
    x = dppAddF<0x128>(x);
    return x;
}

// ---------------- pack kernel: keys/values -> B-frag order + passthrough copies + scal zero
__global__ __launch_bounds__(256) void pack_kernel(
    const float* __restrict__ keys, const float* __restrict__ values,
    unsigned short* __restrict__ keysFrag, unsigned short* __restrict__ valsFrag,
    float* __restrict__ keysOut, float* __restrict__ valsOut,
    float* __restrict__ scal) {
    int tid = blockIdx.x * 256 + threadIdx.x;
    if (tid < 65536) {
        int e  = tid & 32767;
        int l  = e & 63;
        int NT = (e >> 6) & 31;
        int kt = e >> 11;                           // 0..15
        int li = l & 15, q4 = l >> 4;
        unsigned short tmp[8];
        if (tid < 32768) {
            // score GEMM: B[k][n] = keys[n][k], keys is [M, C] row-major
            const float* s = keys + (size_t)(NT * 16 + li) * C_DIM + kt * 32 + q4 * 8;
#pragma unroll
            for (int j = 0; j < 8; j++) tmp[j] = f2bf(s[j]);
            unsigned short* d = keysFrag + ((size_t)(kt * 32 + NT) * 64 + l) * 8;
            *(ushort4*)d       = make_ushort4(tmp[0], tmp[1], tmp[2], tmp[3]);
            *(ushort4*)(d + 4) = make_ushort4(tmp[4], tmp[5], tmp[6], tmp[7]);
        } else {
            // PV GEMM: B[k][n] = values[k][n], k indexes M
#pragma unroll
            for (int j = 0; j < 8; j++)
                tmp[j] = f2bf(values[(size_t)(kt * 32 + q4 * 8 + j) * C_DIM + NT * 16 + li]);
            unsigned short* d = valsFrag + ((size_t)(kt * 32 + NT) * 64 + l) * 8;
            *(ushort4*)d       = make_ushort4(tmp[0], tmp[1], tmp[2], tmp[3]);
            *(ushort4*)(d + 4) = make_ushort4(tmp[4], tmp[5], tmp[6], tmp[7]);
        }
    } else {
        int ct = tid - 65536;                       // 0..32767
        if (ct == 0) { scal[0] = 0.f; scal[1] = 0.f; scal[2] = 0.f; }
#pragma unroll
        for (int i = 0; i < 4; i++) {
            int idx = ct + i * 32768;               // 0..131071 float4s
            if (idx < 65536) ((float4*)keysOut)[idx] = ((const float4*)keys)[idx];
            else             ((float4*)valsOut)[idx - 65536] = ((const float4*)values)[idx - 65536];
        }
    }
}

// ---------------- score kernel: 128 rows/block, 256 blocks (1/CU), chunked load||GEMM.
// 8 chunks of 64 cols: stage chunk c (raw bf16, norm deferred) while GEMM runs
// chunk c's 2 kts right after its barrier; key HBM latency hides under MFMA.
// Staging map: thread t -> row t>>2, 16-float segment t&3 of each 64-col chunk.
__global__ __launch_bounds__(512, 2) void score_kernel(
    const float* __restrict__ key,
    const unsigned short* __restrict__ keysFrag,
    float* __restrict__ outRQ,
    float* __restrict__ scal) {
    __shared__ char kq[ROWS * KQ_STRIDE];             // raw-k bf16 tile -> p tile
    __shared__ __align__(16) float stats[8][ROWS][4];
    __shared__ float invsh[ROWS];

    const int tid = threadIdx.x;
    const int w  = tid >> 6;
    const int l  = tid & 63;
    const int li = l & 15;
    const int q4 = l >> 4;
    const int row0 = blockIdx.x << 7;
    char* outb = (char*)outRQ;

    const int sr = tid >> 2, sq = tid & 3;            // staging row / segment
    const float4* krow = (const float4*)(key + (size_t)(row0 + sr) * C_DIM);
    char* sdst = kq + sr * KQ_STRIDE + sq * 32;

    floatx4 acc1[32];                                 // [rg*4+nt], rg 0..7
#pragma unroll
    for (int i = 0; i < 32; i++) acc1[i] = (floatx4){0.f, 0.f, 0.f, 0.f};

    const short8* kf = (const short8*)keysFrag;
    short8 bcur[4], bnxt[4];
#pragma unroll
    for (int nt = 0; nt < 4; nt++) bcur[nt] = kf[(size_t)((w * 4 + nt) * 64 + l)];

    float4 va[4], vb[4];
#pragma unroll
    for (int j = 0; j < 4; j++) va[j] = krow[sq * 4 + j];   // chunk 0
    float ss = 0.f;

    for (int c = 0; c < 8; ++c) {
        if (c < 7) {
#pragma unroll
            for (int j = 0; j < 4; j++) vb[j] = krow[(c + 1) * 16 + sq * 4 + j];
        }
        // stage chunk c + accumulate sum-of-squares
#pragma unroll
        for (int j = 0; j < 4; j++)
            ss += va[j].x * va[j].x + va[j].y * va[j].y + va[j].z * va[j].z + va[j].w * va[j].w;
        *(ushort4*)(sdst + c * 128) =
            make_ushort4(f2bf(va[0].x), f2bf(va[0].y), f2bf(va[0].z), f2bf(va[0].w));
        *(ushort4*)(sdst + c * 128 + 8) =
            make_ushort4(f2bf(va[1].x), f2bf(va[1].y), f2bf(va[1].z), f2bf(va[1].w));
        *(ushort4*)(sdst + c * 128 + 16) =
            make_ushort4(f2bf(va[2].x), f2bf(va[2].y), f2bf(va[2].z), f2bf(va[2].w));
        *(ushort4*)(sdst + c * 128 + 24) =
            make_ushort4(f2bf(va[3].x), f2bf(va[3].y), f2bf(va[3].z), f2bf(va[3].w));
        __syncthreads();
        // GEMM on this chunk's two kts
#pragma unroll
        for (int k2 = 0; k2 < 2; ++k2) {
            int kt = c * 2 + k2;
            if (kt < 15) {
#pragma unroll
                for (int nt = 0; nt < 4; nt++)
                    bnxt[nt] = kf[(size_t)(((kt + 1) * 32 + w * 4 + nt) * 64 + l)];
            }
#pragma unroll
            for (int rg = 0; rg < 8; ++rg) {
                short8 a = *(const short8*)(kq + (rg * 16 + li) * KQ_STRIDE + kt * 64 + q4 * 16);
#pragma unroll
                for (int nt = 0; nt < 4; nt++)
                    acc1[rg * 4 + nt] = __builtin_amdgcn_mfma_f32_16x16x32_bf16(
                        a, bcur[nt], acc1[rg * 4 + nt], 0, 0, 0);
            }
#pragma unroll
            for (int nt = 0; nt < 4; nt++) bcur[nt] = bnxt[nt];
        }
#pragma unroll
        for (int j = 0; j < 4; j++) va[j] = vb[j];
    }

    // finalize norms: reduce ss across the 4 staging threads of each row (one quad)
    ss = dppAddF<0xB1>(ss);
    ss = dppAddF<0x4E>(ss);
    if (sq == 0) invsh[sr] = 1.0f / fmaxf(sqrtf(ss), 1e-12f);
    __syncthreads();

    // ---- stats (scale by inv-norm, shiftless softmax, DPP reductions), acc1 -> p ----
#pragma unroll
    for (int rg = 0; rg < 8; rg++) {
#pragma unroll
        for (int reg = 0; reg < 4; reg++) {
            const int colbase = (w << 6) + li;
            const float inv = invsh[rg * 16 + q4 * 4 + reg];
            float s0 = acc1[rg * 4 + 0][reg] * inv;
            float s1 = acc1[rg * 4 + 1][reg] * inv;
            float s2 = acc1[rg * 4 + 2][reg] * inv;
            float s3 = acc1[rg * 4 + 3][reg] * inv;
            unsigned K  = skey(s0, colbase);
            unsigned K1 = skey(s1, colbase + 16);
            unsigned K2 = skey(s2, colbase + 32);
            unsigned K3 = skey(s3, colbase + 48);
            K = K1 > K ? K1 : K;
            K = K2 > K ? K2 : K;
            K = K3 > K ? K3 : K;
            float p0 = __expf(s0), p1 = __expf(s1), p2 = __expf(s2), p3 = __expf(s3);
            float z1 = (p0 + p1) + (p2 + p3);
            float e1 = p0 * s0 + p1 * s1 + p2 * s2 + p3 * s3;
            float z2 = p0 * p0 + p1 * p1 + p2 * p2 + p3 * p3;
            acc1[rg * 4 + 0][reg] = p0;
            acc1[rg * 4 + 1][reg] = p1;
            acc1[rg * 4 + 2][reg] = p2;
            acc1[rg * 4 + 3][reg] = p3;
            K = dppMaxU<0xB1>(K);  z1 = dppAddF<0xB1>(z1);  e1 = dppAddF<0xB1>(e1);  z2 = dppAddF<0xB1>(z2);
            K = dppMaxU<0x4E>(K);  z1 = dppAddF<0x4E>(z1);  e1 = dppAddF<0x4E>(e1);  z2 = dppAddF<0x4E>(z2);
            K = dppMaxU<0x124>(K); z1 = dppAddF<0x124>(z1); e1 = dppAddF<0x124>(e1); z2 = dppAddF<0x124>(z2);
            K = dppMaxU<0x128>(K); z1 = dppAddF<0x128>(z1); e1 = dppAddF<0x128>(e1); z2 = dppAddF<0x128>(z2);
            if (li == 0) {
                floatx4 sv;
                sv[0] = __builtin_bit_cast(float, K);
                sv[1] = z1; sv[2] = e1; sv[3] = z2;
                *(floatx4*)stats[w][rg * 16 + q4 * 4 + reg] = sv;
            }
        }
    }
    __syncthreads();

    // ---- merge + headers {iz, idx} + scalars (wave 0; lane l owns rows l and l+64) ----
    if (w == 0) {
        unsigned KA, KB; float z1A, e1A, z2A, z1B, e1B, z2B;
        floatx4 vA = *(const floatx4*)stats[0][l];
        floatx4 vB = *(const floatx4*)stats[0][64 + l];
        KA = __builtin_bit_cast(unsigned, vA[0]); z1A = vA[1]; e1A = vA[2]; z2A = vA[3];
        KB = __builtin_bit_cast(unsigned, vB[0]); z1B = vB[1]; e1B = vB[2]; z2B = vB[3];
#pragma unroll
        for (int p = 1; p < 8; p++) {
            floatx4 uA = *(const floatx4*)stats[p][l];
            floatx4 uB = *(const floatx4*)stats[p][64 + l];
            unsigned KoA = __builtin_bit_cast(unsigned, uA[0]);
            unsigned KoB = __builtin_bit_cast(unsigned, uB[0]);
            KA = KoA > KA ? KoA : KA; z1A += uA[1]; e1A += uA[2]; z2A += uA[3];
            KB = KoB > KB ? KoB : KB; z1B += uB[1]; e1B += uB[2]; z2B += uB[3];
        }
        float izA = 1.0f / z1A, izB = 1.0f / z1B;
        int idxA = 511 - (int)(KA & 0x1FFu);
        int idxB = 511 - (int)(KB & 0x1FFu);
        char* h0 = outb + (size_t)(row0 + l) * 2048;
        char* h1 = outb + (size_t)(row0 + 64 + l) * 2048;
        *(float*)h0 = izA; *(int*)(h0 + 4) = idxA;
        *(float*)h1 = izB; *(int*)(h1 + 4) = idxB;
        unsigned umA = (KA >> 31) ? (KA & 0x7FFFFFFFu) : ~KA;
        unsigned umB = (KB >> 31) ? (KB & 0x7FFFFFFFu) : ~KB;
        umA &= ~0x1FFu; umB &= ~0x1FFu;
        float m1A = __builtin_bit_cast(float, umA);
        float m1B = __builtin_bit_cast(float, umB);
        float ent = (__logf(z1A) - e1A * izA) + (__logf(z1B) - e1B * izB);
        float con = (__logf(z2A) - 2.0f * m1A) + (__logf(z2B) - 2.0f * m1B);
#pragma unroll
        for (int msk = 1; msk < 64; msk <<= 1) {
            ent += __shfl_xor(ent, msk, 64);
            con += __shfl_xor(con, msk, 64);
        }
        if (l == 0) {
            atomicAdd(&scal[0], ent * (1.0f / 32768.0f));
            atomicAdd(&scal[2], con * (1.0f / 12800.0f));
        }
    }

    // ---- p (in acc1) -> bf16, overwrite kq ----
#pragma unroll
    for (int rg = 0; rg < 8; rg++) {
#pragma unroll
        for (int reg = 0; reg < 4; reg++) {
            int r = rg * 16 + q4 * 4 + reg;
#pragma unroll
            for (int nt = 0; nt < 4; nt++) {
                int col = (w << 6) + nt * 16 + li;
                *(unsigned short*)(kq + r * KQ_STRIDE + col * 2) = f2bf(acc1[rg * 4 + nt][reg]);
            }
        }
    }
    __syncthreads();

    // ---- copy p tile -> global (second half of each outRQ row), coalesced 16B ----
#pragma unroll
    for (int it = 0; it < 16; it++) {
        int r = (w << 4) + it;
        float4 t = *(const float4*)(kq + r * KQ_STRIDE + l * 16);
        *(float4*)(outb + (size_t)(row0 + r) * 2048 + 1024 + l * 16) = t;
    }
}

// ---------------- pv kernel: chunked p staging || PV GEMM, scale+store, fused gather.
// Early query touches warm L3 under the GEMM; gather tail then reads near-L3.
__global__ __launch_bounds__(512, 2) void pv_kernel(
    const unsigned short* __restrict__ valsFrag,
    const float* __restrict__ query,
    const float* __restrict__ values,
    float* __restrict__ outRQ,
    float* __restrict__ scal) {
    __shared__ char kq[ROWS * KQ_STRIDE];
    __shared__ float izsh[ROWS];
    __shared__ int   idxsh[ROWS];
    __shared__ float gpart[8];

    const int tid = threadIdx.x;
    const int w  = tid >> 6;
    const int l  = tid & 63;
    const int li = l & 15;
    const int q4 = l >> 4;
    const int row0 = blockIdx.x << 7;
    char* outb = (char*)outRQ;

    // query L3-warm touches: 1 float per 128B line of this block's 256KB query slice
    const float* qtb = query + (size_t)row0 * C_DIM;
    float tch0 = qtb[(tid)        * 32];
    float tch1 = qtb[(tid +  512) * 32];
    float tch2 = qtb[(tid + 1024) * 32];
    float tch3 = qtb[(tid + 1536) * 32];

    if (tid < ROWS) {
        izsh[tid]  = *(const float*)(outb + (size_t)(row0 + tid) * 2048);
        idxsh[tid] = *(const int*)(outb + (size_t)(row0 + tid) * 2048 + 4);
    }

    // staging mapping: thread handles row sr, 32B at byte offset sq*32 of each 128B chunk
    const int sr = tid >> 2, sq = tid & 3;
    const char* psrc = outb + (size_t)(row0 + sr) * 2048 + 1024 + sq * 32;
    char* pdst = kq + sr * KQ_STRIDE + sq * 32;

    floatx4 acc2[32];
#pragma unroll
    for (int i = 0; i < 32; i++) acc2[i] = (floatx4){0.f, 0.f, 0.f, 0.f};

    const short8* vf = (const short8*)valsFrag;
    short8 bcur[4], bnxt[4];
#pragma unroll
    for (int nt = 0; nt < 4; nt++) bcur[nt] = vf[(size_t)((w * 4 + nt) * 64 + l)];

    float4 va0 = *(const float4*)(psrc);
    float4 va1 = *(const float4*)(psrc + 16);
    float4 vb0, vb1;

    for (int c = 0; c < 8; ++c) {
        if (c < 7) {
            vb0 = *(const float4*)(psrc + (c + 1) * 128);
            vb1 = *(const float4*)(psrc + (c + 1) * 128 + 16);
        }
        *(float4*)(pdst + c * 128)      = va0;
        *(float4*)(pdst + c * 128 + 16) = va1;
        __syncthreads();
#pragma unroll
        for (int k2 = 0; k2 < 2; ++k2) {
            int kt = c * 2 + k2;
            if (kt < 15) {
#pragma unroll
                for (int nt = 0; nt < 4; nt++)
                    bnxt[nt] = vf[(size_t)(((kt + 1) * 32 + w * 4 + nt) * 64 + l)];
            }
#pragma unroll
            for (int rg = 0; rg < 8; ++rg) {
                short8 a = *(const short8*)(kq + (rg * 16 + li) * KQ_STRIDE + kt * 64 + q4 * 16);
#pragma unroll
                for (int nt = 0; nt < 4; nt++)
                    acc2[rg * 4 + nt] = __builtin_amdgcn_mfma_f32_16x16x32_bf16(
                        a, bcur[nt], acc2[rg * 4 + nt], 0, 0, 0);
            }
#pragma unroll
            for (int nt = 0; nt < 4; nt++) bcur[nt] = bnxt[nt];
        }
        va0 = vb0; va1 = vb1;
    }
    asm volatile("" :: "v"(tch0), "v"(tch1), "v"(tch2), "v"(tch3));

    // ---- scale by iz (LDS broadcast) and store; overwrites headers+p with result ----
#pragma unroll
    for (int rg = 0; rg < 8; rg++) {
#pragma unroll
        for (int reg = 0; reg < 4; reg++) {
            int r = rg * 16 + q4 * 4 + reg;
            float izr = izsh[r];
            float* orow = outRQ + (size_t)(row0 + r) * C_DIM + (w << 6) + li;
#pragma unroll
            for (int nt = 0; nt < 4; nt++) orow[nt * 16] = acc2[rg * 4 + nt][reg] * izr;
        }
    }

    // ---- fused gathering loss: mean((q_norm - values[idx])^2), 16 rows per wave ----
    float gacc = 0.f;
#pragma unroll
    for (int rr = 0; rr < 16; rr++) {
        int r = (w << 4) + rr;
        int idxr = idxsh[r];
        const float4* qr = (const float4*)(query + (size_t)(row0 + r) * C_DIM);
        float4 a = qr[l * 2], b = qr[l * 2 + 1];
        float ss = a.x * a.x + a.y * a.y + a.z * a.z + a.w * a.w +
                   b.x * b.x + b.y * b.y + b.z * b.z + b.w * b.w;
        ss = rowAdd16(ss);
        ss += __shfl_xor(ss, 16, 64);
        ss += __shfl_xor(ss, 32, 64);
        float inv = 1.0f / fmaxf(sqrtf(ss), 1e-12f);
        const float4* vr = (const float4*)(values + (size_t)idxr * C_DIM);
        float4 va = vr[l * 2], vb = vr[l * 2 + 1];
        float d;
        d = a.x * inv - va.x; gacc += d * d;
        d = a.y * inv - va.y; gacc += d * d;
        d = a.z * inv - va.z; gacc += d * d;
        d = a.w * inv - va.w; gacc += d * d;
        d = b.x * inv - vb.x; gacc += d * d;
        d = b.y * inv - vb.y; gacc += d * d;
        d = b.z * inv - vb.z; gacc += d * d;
        d = b.w * inv - vb.w; gacc += d * d;
    }
    gacc = rowAdd16(gacc);
    gacc += __shfl_xor(gacc, 16, 64);
    gacc += __shfl_xor(gacc, 32, 64);
    if (l == 0) gpart[w] = gacc;
    __syncthreads();
    if (tid == 0) {
        float s = 0.f;
#pragma unroll
        for (int i = 0; i < 8; i++) s += gpart[i];
        atomicAdd(&scal[1], s * (1.0f / (32768.0f * 512.0f)));
    }
}

extern "C" void kernel_launch(void* const* d_in, const int* in_sizes, int n_in,
                              void* d_out, int out_size, void* d_ws, size_t ws_size,
                              hipStream_t stream) {
    (void)in_sizes; (void)n_in; (void)out_size; (void)ws_size;
    const float* key    = (const float*)d_in[0];
    const float* query  = (const float*)d_in[1];
    const float* keysIn = (const float*)d_in[2];
    const float* valsIn = (const float*)d_in[3];
    float* out = (float*)d_out;

    unsigned short* keysFrag = (unsigned short*)d_ws;            // 512 KB
    unsigned short* valsFrag = keysFrag + 512 * 512;             // 512 KB

    float* outRQ   = out;                       // 16777216 floats
    float* scal    = out + 16777216;            // entropy, gathering, contrast
    float* keysOut = out + 16777219;            // 262144 floats
    float* valsOut = keysOut + 262144;          // 262144 floats

    pack_kernel<<<384, 256, 0, stream>>>(keysIn, valsIn, keysFrag, valsFrag,
                                         keysOut, valsOut, scal);
    score_kernel<<<256, 512, 0, stream>>>(key, keysFrag, outRQ, scal);
    pv_kernel<<<256, 512, 0, stream>>>(valsFrag, query, valsIn, outRQ, scal);
}

// Round 10
// 227.286 us; speedup vs baseline: 1.0655x; 1.0457x over previous
//
#include <hip/hip_runtime.h>

typedef short short8 __attribute__((ext_vector_type(8)));
typedef float floatx4 __attribute__((ext_vector_type(4)));

#define C_DIM 512
#define KQ_STRIDE 1040   // bytes per row of the LDS tile (512*2 + 16 pad)
#define ROWS 128         // rows per block (score + pv), 1 block/CU

__device__ __forceinline__ unsigned short f2bf(float f) {
    unsigned u = __builtin_bit_cast(unsigned, f);
    u = u + 0x7fffu + ((u >> 16) & 1u);
    return (unsigned short)(u >> 16);
}

// Monotone uint key for argmax (max s, then min col); 9 low bits carry 511-col.
__device__ __forceinline__ unsigned skey(float s, int col) {
    unsigned u = __builtin_bit_cast(unsigned, s);
    u = ((int)u < 0) ? ~u : (u | 0x80000000u);
    return (u & ~0x1FFu) | (unsigned)(511 - col);
}

// ---- DPP 16-lane-row reductions on the VALU pipe ----
template <int CTRL>
__device__ __forceinline__ float dppAddF(float x) {
    int t = __builtin_amdgcn_update_dpp(0, __builtin_bit_cast(int, x), CTRL, 0xF, 0xF, true);
    return x + __builtin_bit_cast(float, t);
}
template <int CTRL>
__device__ __forceinline__ unsigned dppMaxU(unsigned x) {
    unsigned u = (unsigned)__builtin_amdgcn_update_dpp(0, (int)x, CTRL, 0xF, 0xF, true);
    return u > x ? u : x;
}
__device__ __forceinline__ float rowAdd16(float x) {
    x = dppAddF<0xB1>(x);
    x = dppAddF<0x4E>(x);
    x = dppAddF<0x124>(x);
    x = dppAddF<0x128>(x);
    return x;
}

// ---------------- pack kernel: keys/values -> B-frag order + passthrough copies + scal zero
__global__ __launch_bounds__(256) void pack_kernel(
    const float* __restrict__ keys, const float* __restrict__ values,
    unsigned short* __restrict__ keysFrag, unsigned short* __restrict__ valsFrag,
    float* __restrict__ keysOut, float* __restrict__ valsOut,
    float* __restrict__ scal) {
    int tid = blockIdx.x * 256 + threadIdx.x;
    if (tid < 65536) {
        int e  = tid & 32767;
        int l  = e & 63;
        int NT = (e >> 6) & 31;
        int kt = e >> 11;                           // 0..15
        int li = l & 15, q4 = l >> 4;
        unsigned short tmp[8];
        if (tid < 32768) {
            // score GEMM: B[k][n] = keys[n][k], keys is [M, C] row-major
            const float* s = keys + (size_t)(NT * 16 + li) * C_DIM + kt * 32 + q4 * 8;
#pragma unroll
            for (int j = 0; j < 8; j++) tmp[j] = f2bf(s[j]);
            unsigned short* d = keysFrag + ((size_t)(kt * 32 + NT) * 64 + l) * 8;
            *(ushort4*)d       = make_ushort4(tmp[0], tmp[1], tmp[2], tmp[3]);
            *(ushort4*)(d + 4) = make_ushort4(tmp[4], tmp[5], tmp[6], tmp[7]);
        } else {
            // PV GEMM: B[k][n] = values[k][n], k indexes M
#pragma unroll
            for (int j = 0; j < 8; j++)
                tmp[j] = f2bf(values[(size_t)(kt * 32 + q4 * 8 + j) * C_DIM + NT * 16 + li]);
            unsigned short* d = valsFrag + ((size_t)(kt * 32 + NT) * 64 + l) * 8;
            *(ushort4*)d       = make_ushort4(tmp[0], tmp[1], tmp[2], tmp[3]);
            *(ushort4*)(d + 4) = make_ushort4(tmp[4], tmp[5], tmp[6], tmp[7]);
        }
    } else {
        int ct = tid - 65536;                       // 0..32767
        if (ct == 0) { scal[0] = 0.f; scal[1] = 0.f; scal[2] = 0.f; }
#pragma unroll
        for (int i = 0; i < 4; i++) {
            int idx = ct + i * 32768;               // 0..131071 float4s
            if (idx < 65536) ((float4*)keysOut)[idx] = ((const float4*)keys)[idx];
            else             ((float4*)valsOut)[idx - 65536] = ((const float4*)values)[idx - 65536];
        }
    }
}

// ---------------- score kernel: 128 rows/block, 256 blocks (1/CU), chunked load||GEMM.
// 8 chunks of 64 cols: stage chunk c (raw bf16, norm deferred) while GEMM runs
// chunk c's 2 kts right after its barrier; key HBM latency hides under MFMA.
// Staging map: thread t -> row t>>2, 16-float segment t&3 of each 64-col chunk.
__global__ __launch_bounds__(512, 2) void score_kernel(
    const float* __restrict__ key,
    const unsigned short* __restrict__ keysFrag,
    float* __restrict__ outRQ,
    float* __restrict__ scal) {
    __shared__ char kq[ROWS * KQ_STRIDE];             // raw-k bf16 tile -> p tile
    __shared__ __align__(16) float stats[8][ROWS][4];
    __shared__ float invsh[ROWS];

    const int tid = threadIdx.x;
    const int w  = tid >> 6;
    const int l  = tid & 63;
    const int li = l & 15;
    const int q4 = l >> 4;
    const int row0 = blockIdx.x << 7;
    char* outb = (char*)outRQ;

    const int sr = tid >> 2, sq = tid & 3;            // staging row / segment
    const float4* krow = (const float4*)(key + (size_t)(row0 + sr) * C_DIM);
    char* sdst = kq + sr * KQ_STRIDE + sq * 32;

    floatx4 acc1[32];                                 // [rg*4+nt], rg 0..7
#pragma unroll
    for (int i = 0; i < 32; i++) acc1[i] = (floatx4){0.f, 0.f, 0.f, 0.f};

    const short8* kf = (const short8*)keysFrag;
    short8 bcur[4], bnxt[4];
#pragma unroll
    for (int nt = 0; nt < 4; nt++) bcur[nt] = kf[(size_t)((w * 4 + nt) * 64 + l)];

    float4 va[4], vb[4];
#pragma unroll
    for (int j = 0; j < 4; j++) va[j] = krow[sq * 4 + j];   // chunk 0
    float ss = 0.f;

    for (int c = 0; c < 8; ++c) {
        if (c < 7) {
#pragma unroll
            for (int j = 0; j < 4; j++) vb[j] = krow[(c + 1) * 16 + sq * 4 + j];
        }
        // stage chunk c + accumulate sum-of-squares
#pragma unroll
        for (int j = 0; j < 4; j++)
            ss += va[j].x * va[j].x + va[j].y * va[j].y + va[j].z * va[j].z + va[j].w * va[j].w;
        *(ushort4*)(sdst + c * 128) =
            make_ushort4(f2bf(va[0].x), f2bf(va[0].y), f2bf(va[0].z), f2bf(va[0].w));
        *(ushort4*)(sdst + c * 128 + 8) =
            make_ushort4(f2bf(va[1].x), f2bf(va[1].y), f2bf(va[1].z), f2bf(va[1].w));
        *(ushort4*)(sdst + c * 128 + 16) =
            make_ushort4(f2bf(va[2].x), f2bf(va[2].y), f2bf(va[2].z), f2bf(va[2].w));
        *(ushort4*)(sdst + c * 128 + 24) =
            make_ushort4(f2bf(va[3].x), f2bf(va[3].y), f2bf(va[3].z), f2bf(va[3].w));
        __syncthreads();
        // GEMM on this chunk's two kts
#pragma unroll
        for (int k2 = 0; k2 < 2; ++k2) {
            int kt = c * 2 + k2;
            if (kt < 15) {
#pragma unroll
                for (int nt = 0; nt < 4; nt++)
                    bnxt[nt] = kf[(size_t)(((kt + 1) * 32 + w * 4 + nt) * 64 + l)];
            }
#pragma unroll
            for (int rg = 0; rg < 8; ++rg) {
                short8 a = *(const short8*)(kq + (rg * 16 + li) * KQ_STRIDE + kt * 64 + q4 * 16);
#pragma unroll
                for (int nt = 0; nt < 4; nt++)
                    acc1[rg * 4 + nt] = __builtin_amdgcn_mfma_f32_16x16x32_bf16(
                        a, bcur[nt], acc1[rg * 4 + nt], 0, 0, 0);
            }
#pragma unroll
            for (int nt = 0; nt < 4; nt++) bcur[nt] = bnxt[nt];
        }
#pragma unroll
        for (int j = 0; j < 4; j++) va[j] = vb[j];
    }

    // finalize norms: reduce ss across the 4 staging threads of each row (one quad)
    ss = dppAddF<0xB1>(ss);
    ss = dppAddF<0x4E>(ss);
    if (sq == 0) invsh[sr] = 1.0f / fmaxf(sqrtf(ss), 1e-12f);
    __syncthreads();

    // ---- stats (scale by inv-norm, shiftless softmax, DPP reductions), acc1 -> p ----
#pragma unroll
    for (int rg = 0; rg < 8; rg++) {
#pragma unroll
        for (int reg = 0; reg < 4; reg++) {
            const int colbase = (w << 6) + li;
            const float inv = invsh[rg * 16 + q4 * 4 + reg];
            float s0 = acc1[rg * 4 + 0][reg] * inv;
            float s1 = acc1[rg * 4 + 1][reg] * inv;
            float s2 = acc1[rg * 4 + 2][reg] * inv;
            float s3 = acc1[rg * 4 + 3][reg] * inv;
            unsigned K  = skey(s0, colbase);
            unsigned K1 = skey(s1, colbase + 16);
            unsigned K2 = skey(s2, colbase + 32);
            unsigned K3 = skey(s3, colbase + 48);
            K = K1 > K ? K1 : K;
            K = K2 > K ? K2 : K;
            K = K3 > K ? K3 : K;
            float p0 = __expf(s0), p1 = __expf(s1), p2 = __expf(s2), p3 = __expf(s3);
            float z1 = (p0 + p1) + (p2 + p3);
            float e1 = p0 * s0 + p1 * s1 + p2 * s2 + p3 * s3;
            float z2 = p0 * p0 + p1 * p1 + p2 * p2 + p3 * p3;
            acc1[rg * 4 + 0][reg] = p0;
            acc1[rg * 4 + 1][reg] = p1;
            acc1[rg * 4 + 2][reg] = p2;
            acc1[rg * 4 + 3][reg] = p3;
            K = dppMaxU<0xB1>(K);  z1 = dppAddF<0xB1>(z1);  e1 = dppAddF<0xB1>(e1);  z2 = dppAddF<0xB1>(z2);
            K = dppMaxU<0x4E>(K);  z1 = dppAddF<0x4E>(z1);  e1 = dppAddF<0x4E>(e1);  z2 = dppAddF<0x4E>(z2);
            K = dppMaxU<0x124>(K); z1 = dppAddF<0x124>(z1); e1 = dppAddF<0x124>(e1); z2 = dppAddF<0x124>(z2);
            K = dppMaxU<0x128>(K); z1 = dppAddF<0x128>(z1); e1 = dppAddF<0x128>(e1); z2 = dppAddF<0x128>(z2);
            if (li == 0) {
                floatx4 sv;
                sv[0] = __builtin_bit_cast(float, K);
                sv[1] = z1; sv[2] = e1; sv[3] = z2;
                *(floatx4*)stats[w][rg * 16 + q4 * 4 + reg] = sv;
            }
        }
    }
    __syncthreads();

    // ---- merge + headers {iz, idx} + scalars (wave 0; lane l owns rows l and l+64) ----
    if (w == 0) {
        unsigned KA, KB; float z1A, e1A, z2A, z1B, e1B, z2B;
        floatx4 vA = *(const floatx4*)stats[0][l];
        floatx4 vB = *(const floatx4*)stats[0][64 + l];
        KA = __builtin_bit_cast(unsigned, vA[0]); z1A = vA[1]; e1A = vA[2]; z2A = vA[3];
        KB = __builtin_bit_cast(unsigned, vB[0]); z1B = vB[1]; e1B = vB[2]; z2B = vB[3];
#pragma unroll
        for (int p = 1; p < 8; p++) {
            floatx4 uA = *(const floatx4*)stats[p][l];
            floatx4 uB = *(const floatx4*)stats[p][64 + l];
            unsigned KoA = __builtin_bit_cast(unsigned, uA[0]);
            unsigned KoB = __builtin_bit_cast(unsigned, uB[0]);
            KA = KoA > KA ? KoA : KA; z1A += uA[1]; e1A += uA[2]; z2A += uA[3];
            KB = KoB > KB ? KoB : KB; z1B += uB[1]; e1B += uB[2]; z2B += uB[3];
        }
        float izA = 1.0f / z1A, izB = 1.0f / z1B;
        int idxA = 511 - (int)(KA & 0x1FFu);
        int idxB = 511 - (int)(KB & 0x1FFu);
        char* h0 = outb + (size_t)(row0 + l) * 2048;
        char* h1 = outb + (size_t)(row0 + 64 + l) * 2048;
        *(float*)h0 = izA; *(int*)(h0 + 4) = idxA;
        *(float*)h1 = izB; *(int*)(h1 + 4) = idxB;
        unsigned umA = (KA >> 31) ? (KA & 0x7FFFFFFFu) : ~KA;
        unsigned umB = (KB >> 31) ? (KB & 0x7FFFFFFFu) : ~KB;
        umA &= ~0x1FFu; umB &= ~0x1FFu;
        float m1A = __builtin_bit_cast(float, umA);
        float m1B = __builtin_bit_cast(float, umB);
        float ent = (__logf(z1A) - e1A * izA) + (__logf(z1B) - e1B * izB);
        float con = (__logf(z2A) - 2.0f * m1A) + (__logf(z2B) - 2.0f * m1B);
#pragma unroll
        for (int msk = 1; msk < 64; msk <<= 1) {
            ent += __shfl_xor(ent, msk, 64);
            con += __shfl_xor(con, msk, 64);
        }
        if (l == 0) {
            atomicAdd(&scal[0], ent * (1.0f / 32768.0f));
            atomicAdd(&scal[2], con * (1.0f / 12800.0f));
        }
    }

    // ---- p (in acc1) -> bf16, overwrite kq ----
#pragma unroll
    for (int rg = 0; rg < 8; rg++) {
#pragma unroll
        for (int reg = 0; reg < 4; reg++) {
            int r = rg * 16 + q4 * 4 + reg;
#pragma unroll
            for (int nt = 0; nt < 4; nt++) {
                int col = (w << 6) + nt * 16 + li;
                *(unsigned short*)(kq + r * KQ_STRIDE + col * 2) = f2bf(acc1[rg * 4 + nt][reg]);
            }
        }
    }
    __syncthreads();

    // ---- copy p tile -> global (second half of each outRQ row), coalesced 16B ----
#pragma unroll
    for (int it = 0; it < 16; it++) {
        int r = (w << 4) + it;
        float4 t = *(const float4*)(kq + r * KQ_STRIDE + l * 16);
        *(float4*)(outb + (size_t)(row0 + r) * 2048 + 1024 + l * 16) = t;
    }
}

// ---------------- gather kernel: mean((q_norm - values[idx])^2); idx from row headers.
// Full-occupancy standalone (memory-bound; needs the TLP). MUST run before
// pv_kernel, which overwrites the headers.
__global__ __launch_bounds__(256) void gather_kernel(
    const float* __restrict__ query,
    const float* __restrict__ values,
    const float* __restrict__ outRQ,
    float* __restrict__ scal) {
    __shared__ float gpart[4];
    const int tid = threadIdx.x;
    const int w = tid >> 6;
    const int l = tid & 63;
    const char* outb = (const char*)outRQ;
    const int row0 = blockIdx.x * 32;

    float gacc = 0.f;
#pragma unroll
    for (int rr = 0; rr < 8; rr++) {
        int r = row0 + w * 8 + rr;
        int idxr = *(const int*)(outb + (size_t)r * 2048 + 4);
        const float4* qr = (const float4*)(query + (size_t)r * C_DIM);
        float4 a = qr[l * 2], b = qr[l * 2 + 1];
        float ss = a.x * a.x + a.y * a.y + a.z * a.z + a.w * a.w +
                   b.x * b.x + b.y * b.y + b.z * b.z + b.w * b.w;
        ss = rowAdd16(ss);
        ss += __shfl_xor(ss, 16, 64);
        ss += __shfl_xor(ss, 32, 64);
        float inv = 1.0f / fmaxf(sqrtf(ss), 1e-12f);
        const float4* vr = (const float4*)(values + (size_t)idxr * C_DIM);
        float4 va = vr[l * 2], vb = vr[l * 2 + 1];
        float d;
        d = a.x * inv - va.x; gacc += d * d;
        d = a.y * inv - va.y; gacc += d * d;
        d = a.z * inv - va.z; gacc += d * d;
        d = a.w * inv - va.w; gacc += d * d;
        d = b.x * inv - vb.x; gacc += d * d;
        d = b.y * inv - vb.y; gacc += d * d;
        d = b.z * inv - vb.z; gacc += d * d;
        d = b.w * inv - vb.w; gacc += d * d;
    }
    gacc = rowAdd16(gacc);
    gacc += __shfl_xor(gacc, 16, 64);
    gacc += __shfl_xor(gacc, 32, 64);
    if (l == 0) gpart[w] = gacc;
    __syncthreads();
    if (tid == 0) {
        float s = gpart[0] + gpart[1] + gpart[2] + gpart[3];
        atomicAdd(&scal[1], s * (1.0f / (32768.0f * 512.0f)));
    }
}

// ---------------- pv kernel: chunked p staging || PV GEMM, scale by iz, store outRQ
__global__ __launch_bounds__(512, 2) void pv_kernel(
    const unsigned short* __restrict__ valsFrag,
    float* __restrict__ outRQ) {
    __shared__ char kq[ROWS * KQ_STRIDE];
    __shared__ float izsh[ROWS];

    const int tid = threadIdx.x;
    const int w  = tid >> 6;
    const int l  = tid & 63;
    const int li = l & 15;
    const int q4 = l >> 4;
    const int row0 = blockIdx.x << 7;
    char* outb = (char*)outRQ;

    if (tid < ROWS) izsh[tid] = *(const float*)(outb + (size_t)(row0 + tid) * 2048);

    // staging mapping: thread handles row sr, 32B at byte offset sq*32 of each 128B chunk
    const int sr = tid >> 2, sq = tid & 3;
    const char* psrc = outb + (size_t)(row0 + sr) * 2048 + 1024 + sq * 32;
    char* pdst = kq + sr * KQ_STRIDE + sq * 32;

    floatx4 acc2[32];
#pragma unroll
    for (int i = 0; i < 32; i++) acc2[i] = (floatx4){0.f, 0.f, 0.f, 0.f};

    const short8* vf = (const short8*)valsFrag;
    short8 bcur[4], bnxt[4];
#pragma unroll
    for (int nt = 0; nt < 4; nt++) bcur[nt] = vf[(size_t)((w * 4 + nt) * 64 + l)];

    float4 va0 = *(const float4*)(psrc);
    float4 va1 = *(const float4*)(psrc + 16);
    float4 vb0, vb1;

    for (int c = 0; c < 8; ++c) {
        if (c < 7) {
            vb0 = *(const float4*)(psrc + (c + 1) * 128);
            vb1 = *(const float4*)(psrc + (c + 1) * 128 + 16);
        }
        *(float4*)(pdst + c * 128)      = va0;
        *(float4*)(pdst + c * 128 + 16) = va1;
        __syncthreads();
#pragma unroll
        for (int k2 = 0; k2 < 2; ++k2) {
            int kt = c * 2 + k2;
            if (kt < 15) {
#pragma unroll
                for (int nt = 0; nt < 4; nt++)
                    bnxt[nt] = vf[(size_t)(((kt + 1) * 32 + w * 4 + nt) * 64 + l)];
            }
#pragma unroll
            for (int rg = 0; rg < 8; ++rg) {
                short8 a = *(const short8*)(kq + (rg * 16 + li) * KQ_STRIDE + kt * 64 + q4 * 16);
#pragma unroll
                for (int nt = 0; nt < 4; nt++)
                    acc2[rg * 4 + nt] = __builtin_amdgcn_mfma_f32_16x16x32_bf16(
                        a, bcur[nt], acc2[rg * 4 + nt], 0, 0, 0);
            }
#pragma unroll
            for (int nt = 0; nt < 4; nt++) bcur[nt] = bnxt[nt];
        }
        va0 = vb0; va1 = vb1;
    }

    // ---- scale by iz (LDS broadcast) and store; overwrites headers+p with result ----
#pragma unroll
    for (int rg = 0; rg < 8; rg++) {
#pragma unroll
        for (int reg = 0; reg < 4; reg++) {
            int r = rg * 16 + q4 * 4 + reg;
            float izr = izsh[r];
            float* orow = outRQ + (size_t)(row0 + r) * C_DIM + (w << 6) + li;
#pragma unroll
            for (int nt = 0; nt < 4; nt++) orow[nt * 16] = acc2[rg * 4 + nt][reg] * izr;
        }
    }
}

extern "C" void kernel_launch(void* const* d_in, const int* in_sizes, int n_in,
                              void* d_out, int out_size, void* d_ws, size_t ws_size,
                              hipStream_t stream) {
    (void)in_sizes; (void)n_in; (void)out_size; (void)ws_size;
    const float* key    = (const float*)d_in[0];
    const float* query  = (const float*)d_in[1];
    const float* keysIn = (const float*)d_in[2];
    const float* valsIn = (const float*)d_in[3];
    float* out = (float*)d_out;

    unsigned short* keysFrag = (unsigned short*)d_ws;            // 512 KB
    unsigned short* valsFrag = keysFrag + 512 * 512;             // 512 KB

    float* outRQ   = out;                       // 16777216 floats
    float* scal    = out + 16777216;            // entropy, gathering, contrast
    float* keysOut = out + 16777219;            // 262144 floats
    float* valsOut = keysOut + 262144;          // 262144 floats

    pack_kernel<<<384, 256, 0, stream>>>(keysIn, valsIn, keysFrag, valsFrag,
                                         keysOut, valsOut, scal);
    score_kernel<<<256, 512, 0, stream>>>(key, keysFrag, outRQ, scal);
    gather_kernel<<<1024, 256, 0, stream>>>(query, valsIn, outRQ, scal);
    pv_kernel<<<256, 512, 0, stream>>>(valsFrag, outRQ);
}